// Round 9
// baseline (136.251 us; speedup 1.0000x reference)
//
#include <hip/hip_runtime.h>
#include <math.h>

#define N_B 16
#define T_LEN 513
#define NTOT (128*513)             // 65,664 floats per batch
#define NQ4  (NTOT/4)              // 16,416 float4s per batch
#define SCALE (1.4426950408889634f/128.0f)   // log2(e)/C

typedef unsigned u32;
typedef unsigned short u16;
typedef short bf16x8 __attribute__((ext_vector_type(8)));
typedef short s16x4 __attribute__((ext_vector_type(4)));
typedef float f32x4 __attribute__((ext_vector_type(4)));

__device__ inline u16 bf16_rne(float f) {
    const u32 u = __builtin_bit_cast(u32, f);
    return (u16)((u + 0x7fffu + ((u >> 16) & 1u)) >> 16);
}
__device__ inline float bl2f(u16 h) {
    return __builtin_bit_cast(float, (u32)h << 16);
}
__device__ inline void cvt8(const float* fa, bf16x8& hv, bf16x8& lv) {
    union { u32 w[4]; bf16x8 v; } H, L;
    #pragma unroll
    for (int p = 0; p < 4; ++p) {
        const float a = fa[2*p], b = fa[2*p+1];
        const u16 ha = bf16_rne(a), hb = bf16_rne(b);
        const u16 la = bf16_rne(a - bl2f(ha)), lb = bf16_rne(b - bl2f(hb));
        H.w[p] = (u32)ha | ((u32)hb << 16);
        L.w[p] = (u32)la | ((u32)lb << 16);
    }
    hv = H.v; lv = L.v;
}
// exact c = e/513 for e < 65,664  (since 513*33489024 = 2^34 + 128)
__device__ inline u32 div513(u32 e) {
    return (u32)(((unsigned long long)e * 33489024ull) >> 34);
}

// One block owns one batch n. grid=16, block=512. Zero cross-block deps.
__global__ __launch_bounds__(512, 1) void k_all(const float* __restrict__ x,
                                                float* __restrict__ ws,
                                                float* __restrict__ out) {
    __shared__ alignas(16) char smraw[140848];
    float* ArT = (float*)smraw;                   // phase A: [128][260] fp32 (transposed)
    u16*  BhS  = (u16*)smraw;                     // phase B: [256][132] bf16-hi
    u16*  BlS  = (u16*)(smraw + 67584);           //          [256][132] bf16-lo
    float* a256 = (float*)(smraw + 135168);       // 128   raw x1[:,256]
    float* ps   = a256 + 128;                     // 260   P_i (0..256)
    float* qs   = ps + 260;                       // 256   Q_j
    float* das  = qs + 256;                       // 256   da -> w
    float* r256 = das + 256;                      // 256   row-256 dots -> RAM row 256
    float* fs   = r256 + 256;                     // 260   final per-i factor
    float* scal = fs + 260;                       // 4     [t0_256, db_256]

    const int n = blockIdx.x;
    const int tid = threadIdx.x;
    const int l = tid & 63, wv = tid >> 6;
    const int il = l & 15, g = l >> 4;
    const int i0 = (wv >> 1) * 64;                // 64-row band per wave pair
    const int jhalf = (wv & 1) * 128;             // j-half per wave
    const float* xn = x + (size_t)n * NTOT;
    float* rn = ws + (size_t)n * 65536;           // RAM rows 0..255

    // ---- 0: zero LDS accumulators (ps,qs,das,r256 contiguous = 1028 floats)
    for (int k = tid; k < 1028; k += 512) ps[k] = 0.f;
    if (tid < 4) scal[tid] = 0.f;
    __syncthreads();

    // ---- 1: sweep 1 — even plane -> ArT (+ a256) + P sums
    for (int it = 0; it <= 32; ++it) {
        const int q = it * 512 + tid;
        if (q < NQ4) {
            const float4 v = *(const float4*)(xn + 4 * (size_t)q);
            const float vv[4] = {v.x, v.y, v.z, v.w};
            #pragma unroll
            for (int k = 0; k < 4; ++k) {
                const u32 e = 4 * q + k;
                const u32 c = div513(e);
                const u32 t = e - 513 * c;
                if (!(t & 1)) {
                    const float f = vv[k];
                    const u32 i = t >> 1;
                    if (i < 256) ArT[c * 260 + i] = f;
                    else         a256[c] = f;
                    atomicAdd(&ps[i], f * f);
                }
            }
        }
    }
    __syncthreads();

    // ---- 2: persistent A-frags (64-row band, hi/lo bf16) + pv preload
    bf16x8 ah[4][4], al[4][4];
    #pragma unroll
    for (int st = 0; st < 4; ++st) {
        #pragma unroll
        for (int kc = 0; kc < 4; ++kc) {
            const int i = i0 + st * 16 + il;
            const int cb = kc * 32 + g * 8;
            float fa[8];
            #pragma unroll
            for (int e = 0; e < 8; ++e) fa[e] = ArT[(cb + e) * 260 + i];
            cvt8(fa, ah[st][kc], al[st][kc]);
        }
    }
    float4 pv[4];
    #pragma unroll
    for (int st = 0; st < 4; ++st)
        pv[st] = *(const float4*)&ps[i0 + st * 16 + g * 4];
    __syncthreads();                               // ArT fully consumed

    // ---- 3: sweep 2 — odd plane -> Bh/Bl planes + Q sums
    for (int it = 0; it <= 32; ++it) {
        const int q = it * 512 + tid;
        if (q < NQ4) {
            const float4 v = *(const float4*)(xn + 4 * (size_t)q);
            const float vv[4] = {v.x, v.y, v.z, v.w};
            #pragma unroll
            for (int k = 0; k < 4; ++k) {
                const u32 e = 4 * q + k;
                const u32 c = div513(e);
                const u32 t = e - 513 * c;
                if (t & 1) {
                    const float f = vv[k];
                    const u32 j = t >> 1;
                    const u16 hb = bf16_rne(f);
                    const u16 lb = bf16_rne(f - bl2f(hb));
                    BhS[j * 132 + c] = hb;
                    BlS[j * 132 + c] = lb;
                    atomicAdd(&qs[j], f * f);
                }
            }
        }
    }
    __syncthreads();

    // ---- 4: row-256 GEMV partial dots (bf16 hi+lo reconstruct ~ fp32)
    {
        const int j = tid & 255, cs2 = tid >> 8;
        float dot = 0.f;
        #pragma unroll 8
        for (int c = cs2 * 64; c < cs2 * 64 + 64; ++c) {
            const float b = bl2f(BhS[j * 132 + c]) + bl2f(BlS[j * 132 + c]);
            dot = fmaf(a256[c], b, dot);
        }
        atomicAdd(&r256[j], dot);
    }

    // ---- 5: pass 1 — MFMA tiles, RAM -> global, da column sums
    for (int ch = 0; ch < 8; ++ch) {
        const int j0 = jhalf + ch * 16;
        f32x4 acc[4];
        #pragma unroll
        for (int st = 0; st < 4; ++st) acc[st] = (f32x4){0.f, 0.f, 0.f, 0.f};
        #pragma unroll
        for (int kc = 0; kc < 4; ++kc) {
            union { bf16x8 v; s16x4 h[2]; } BH, BL;
            const int soff = (j0 + il) * 132 + kc * 32 + g * 8;
            BH.h[0] = *(const s16x4*)(BhS + soff);
            BH.h[1] = *(const s16x4*)(BhS + soff + 4);
            BL.h[0] = *(const s16x4*)(BlS + soff);
            BL.h[1] = *(const s16x4*)(BlS + soff + 4);
            #pragma unroll
            for (int st = 0; st < 4; ++st) {
                acc[st] = __builtin_amdgcn_mfma_f32_16x16x32_bf16(ah[st][kc], BH.v, acc[st], 0, 0, 0);
                acc[st] = __builtin_amdgcn_mfma_f32_16x16x32_bf16(ah[st][kc], BL.v, acc[st], 0, 0, 0);
                acc[st] = __builtin_amdgcn_mfma_f32_16x16x32_bf16(al[st][kc], BH.v, acc[st], 0, 0, 0);
            }
        }
        const float qv = qs[j0 + il];
        float colp = 0.f;
        #pragma unroll
        for (int st = 0; st < 4; ++st) {
            #pragma unroll
            for (int r = 0; r < 4; ++r) {
                const int i = i0 + st * 16 + g * 4 + r;
                const float rv = exp2f((pv[st][r] + qv - 2.f * acc[st][r]) * SCALE);
                rn[i * 256 + j0 + il] = rv;       // RAM >= 1: 0.5-threshold dead
                colp += rv;
            }
        }
        colp += __shfl_xor(colp, 16, 64);
        colp += __shfl_xor(colp, 32, 64);
        if (l < 16) atomicAdd(&das[j0 + l], colp);
    }
    __syncthreads();                               // das/r256 complete, rn drained

    // ---- 6: finalize row 256; das -> w = rsqrt(da)
    if (tid < 256) {
        const int j = tid;
        const float rv = exp2f((ps[256] + qs[j] - 2.f * r256[j]) * SCALE);
        r256[j] = rv;
        das[j] = rsqrtf(das[j] + rv);              // da >= 257, eps negligible
    }
    __syncthreads();

    // ---- 7: pass 2 — stream RAM rows: db + weighted rowsum -> fs
    {
        const float4 w4 = *(const float4*)&das[4 * l];
        #pragma unroll 4
        for (int rr = 0; rr < 32; ++rr) {
            const int i = wv * 32 + rr;
            const float4 v = *(const float4*)&rn[i * 256 + 4 * l];
            float t0 = v.x * w4.x + v.y * w4.y + v.z * w4.z + v.w * w4.w;
            float db = v.x + v.y + v.z + v.w;
            #pragma unroll
            for (int o = 32; o; o >>= 1) {
                t0 += __shfl_xor(t0, o, 64);
                db += __shfl_xor(db, o, 64);
            }
            if (l == 0) fs[i] = 2.f * t0 * rsqrtf(db);
        }
        if (tid < 256) {                           // row 256 (waves 0..3)
            float t0 = r256[tid] * das[tid];
            float db = r256[tid];
            #pragma unroll
            for (int o = 32; o; o >>= 1) {
                t0 += __shfl_xor(t0, o, 64);
                db += __shfl_xor(db, o, 64);
            }
            if (l == 0) { atomicAdd(&scal[0], t0); atomicAdd(&scal[1], db); }
        }
    }
    __syncthreads();
    if (tid == 0) fs[256] = 2.f * scal[0] * rsqrtf(scal[1]);
    __syncthreads();

    // ---- 8: fused apply: out = x * 2 * rowsum[t>>1]
    float* on = out + (size_t)n * NTOT;
    for (int it = 0; it <= 32; ++it) {
        const int q = it * 512 + tid;
        if (q < NQ4) {
            const float4 v = *(const float4*)(xn + 4 * (size_t)q);
            const float vv[4] = {v.x, v.y, v.z, v.w};
            float ov[4];
            #pragma unroll
            for (int k = 0; k < 4; ++k) {
                const u32 e = 4 * q + k;
                const u32 c = div513(e);
                const u32 t = e - 513 * c;
                ov[k] = vv[k] * fs[t >> 1];
            }
            float4 o4; o4.x = ov[0]; o4.y = ov[1]; o4.z = ov[2]; o4.w = ov[3];
            *(float4*)(on + 4 * (size_t)q) = o4;
        }
    }
}

extern "C" void kernel_launch(void* const* d_in, const int* in_sizes, int n_in,
                              void* d_out, int out_size, void* d_ws, size_t ws_size,
                              hipStream_t stream) {
    const float* x = (const float*)d_in[0];
    float* out = (float*)d_out;
    float* ws = (float*)d_ws;
    k_all<<<N_B, 512, 0, stream>>>(x, ws, out);
}

// Round 10
// 26.394 us; speedup vs baseline: 5.1622x; 5.1622x over previous
//
#include <hip/hip_runtime.h>
#include <math.h>

#define N_B 16
#define C_CH 128
#define T_LEN 513
#define NI 257
#define NJ 256
#define SCALE (1.4426950408889634f/128.0f)     // log2(e)/C

typedef unsigned u32;
typedef unsigned short u16;
typedef short bf16x8 __attribute__((ext_vector_type(8)));
typedef float f32x4 __attribute__((ext_vector_type(4)));

// workspace: RAM f32[16][257][256] @0 ; pda f32[16][17][256]
#define RAM_F 0
#define PDA_F (N_B*NI*NJ)

__device__ inline u16 bf16_rne(float f) {
    const u32 u = __builtin_bit_cast(u32, f);
    return (u16)((u + 0x7fffu + ((u >> 16) & 1u)) >> 16);
}
__device__ inline float bl2f(u16 h) {
    return __builtin_bit_cast(float, (u32)h << 16);
}
__device__ inline void cvt8(const float* fa, bf16x8& hv, bf16x8& lv) {
    union { u32 w[4]; bf16x8 v; } H, L;
    #pragma unroll
    for (int p = 0; p < 4; ++p) {
        const float a = fa[2*p], b = fa[2*p+1];
        const u16 ha = bf16_rne(a), hb = bf16_rne(b);
        const u16 la = bf16_rne(a - bl2f(ha)), lb = bf16_rne(b - bl2f(hb));
        H.w[p] = (u32)ha | ((u32)hb << 16);
        L.w[p] = (u32)la | ((u32)lb << 16);
    }
    hv = H.v; lv = L.v;
}

// ---------------- K1: grid (jh=2, ib=17, n=16) = 544 blocks x 512 thr.
// Block stages B odd-plane half [128j][128c] + A rows [16][128c] in LDS (76 KB),
// one sync, 1 MFMA tile/wave (hi/lo bf16), writes RAM + pda column partials.
__global__ __launch_bounds__(512, 4) void k1(const float* __restrict__ x,
                                             float* __restrict__ ram,
                                             float* __restrict__ pda) {
    __shared__ float Bs[128][132];
    __shared__ float As[16][132];
    const int jh = blockIdx.x, ib = blockIdx.y, n = blockIdx.z;
    const int i0 = ib * 16, T0 = jh * 256;
    const int tid = threadIdx.x;
    const float* xn = x + (size_t)n * (C_CH * T_LEN);

    {   // stage A: even t = 2*i0 .. 2*i0+30 (zero-pad t>512)
        const int c = tid >> 2, k = tid & 3;
        #pragma unroll
        for (int m = 0; m < 4; ++m) {
            const int t = 2 * i0 + 8 * k + 2 * m;
            As[4 * k + m][c] = (t <= 512) ? xn[c * T_LEN + t] : 0.f;
        }
    }
    {   // stage B: contiguous t-window [T0, T0+256); odd lanes keep odd t
        const int w = tid >> 6, l = tid & 63;
        #pragma unroll
        for (int cc = 0; cc < 16; ++cc) {
            const int c = w * 16 + cc;
            #pragma unroll
            for (int p = 0; p < 4; ++p) {
                const int toff = p * 64 + l;
                const float f = xn[c * T_LEN + T0 + toff];
                if (toff & 1) Bs[toff >> 1][c] = f;
            }
        }
    }
    __syncthreads();

    const int l = tid & 63, wvi = tid >> 6;
    const int il = l & 15, g = l >> 4;
    bf16x8 ah[4], al[4], bh[4], bl[4];
    float psum = 0.f, qsq = 0.f;
    #pragma unroll
    for (int kc = 0; kc < 4; ++kc) {
        float fa[8], fb[8];
        const float* ap = &As[il][kc * 32 + 8 * g];
        const float* bp = &Bs[wvi * 16 + il][kc * 32 + 8 * g];
        #pragma unroll
        for (int e = 0; e < 8; ++e) { fa[e] = ap[e]; fb[e] = bp[e]; }
        #pragma unroll
        for (int e = 0; e < 8; ++e) {
            psum = fmaf(fa[e], fa[e], psum);
            qsq  = fmaf(fb[e], fb[e], qsq);
        }
        cvt8(fa, ah[kc], al[kc]);
        cvt8(fb, bh[kc], bl[kc]);
    }
    psum += __shfl_xor(psum, 16, 64);
    psum += __shfl_xor(psum, 32, 64);             // P[i0+il] replicated
    qsq  += __shfl_xor(qsq, 16, 64);
    qsq  += __shfl_xor(qsq, 32, 64);              // Q[j] replicated
    float pv[4];
    #pragma unroll
    for (int r = 0; r < 4; ++r) pv[r] = __shfl(psum, 4 * g + r, 64);

    f32x4 acc = {0.f, 0.f, 0.f, 0.f};
    #pragma unroll
    for (int kc = 0; kc < 4; ++kc) {
        acc = __builtin_amdgcn_mfma_f32_16x16x32_bf16(ah[kc], bh[kc], acc, 0, 0, 0);
        acc = __builtin_amdgcn_mfma_f32_16x16x32_bf16(ah[kc], bl[kc], acc, 0, 0, 0);
        acc = __builtin_amdgcn_mfma_f32_16x16x32_bf16(al[kc], bh[kc], acc, 0, 0, 0);
    }
    const int j0 = jh * 128 + wvi * 16;
    float cs = 0.f;
    float* rn = ram + (size_t)n * NI * NJ;
    #pragma unroll
    for (int r = 0; r < 4; ++r) {
        const int i = i0 + 4 * g + r;
        const float rv = exp2f((pv[r] + qsq - 2.f * acc[r]) * SCALE);
        if (i < NI) { rn[(size_t)i * NJ + j0 + il] = rv; cs += rv; }   // RAM>=1: 0.5-thr dead
    }
    cs += __shfl_xor(cs, 16, 64);
    cs += __shfl_xor(cs, 32, 64);
    if (l < 16) pda[((size_t)n * 17 + ib) * NJ + j0 + l] = cs;
}

// ---------------- K2: w_j=rsqrt(da); per-row db + weighted rowsum; fused apply. (R4-proven)
__global__ __launch_bounds__(256) void k2(const float* __restrict__ ram,
                                          const float* __restrict__ pda,
                                          const float* __restrict__ x,
                                          float* __restrict__ out) {
    const int ic = blockIdx.x, n = blockIdx.y;
    __shared__ float w_s[NJ];
    __shared__ float f_s[16];
    const int tid = threadIdx.x;
    {
        float da = 0.f;
        #pragma unroll
        for (int k = 0; k < 17; ++k) da += pda[((size_t)n * 17 + k) * NJ + tid];
        w_s[tid] = rsqrtf(da);                    // da >= 257, eps negligible
    }
    __syncthreads();
    const int wv = tid >> 6, lane = tid & 63;
    #pragma unroll
    for (int rr = 0; rr < 4; ++rr) {
        const int lr = wv * 4 + rr;
        const int i = ic * 16 + lr;
        if (i < NI) {
            const float* rrow = ram + ((size_t)n * NI + i) * NJ;
            float db = 0.f, t0 = 0.f;
            #pragma unroll
            for (int k = 0; k < 4; ++k) {
                const float v = rrow[lane + 64 * k];
                db += v;
                t0 = fmaf(v, w_s[lane + 64 * k], t0);
            }
            #pragma unroll
            for (int off = 32; off; off >>= 1) {
                db += __shfl_xor(db, off, 64);
                t0 += __shfl_xor(t0, off, 64);
            }
            if (lane == 0) f_s[lr] = 2.f * t0 * rsqrtf(db);
        }
    }
    __syncthreads();
    const int tt = tid & 31, cgp = tid >> 5;
    const int t = ic * 32 + tt;
    if (t < T_LEN) {
        const float f = f_s[tt >> 1];
        const float* xn = x + (size_t)n * C_CH * T_LEN;
        float* on = out + (size_t)n * C_CH * T_LEN;
        #pragma unroll
        for (int p = 0; p < 16; ++p) {
            const int c = cgp * 16 + p;
            on[c * T_LEN + t] = xn[c * T_LEN + t] * f;
        }
    }
}

extern "C" void kernel_launch(void* const* d_in, const int* in_sizes, int n_in,
                              void* d_out, int out_size, void* d_ws, size_t ws_size,
                              hipStream_t stream) {
    const float* x = (const float*)d_in[0];
    float* out = (float*)d_out;
    float* ws = (float*)d_ws;
    float* ram = ws + RAM_F;
    float* pda = ws + PDA_F;

    k1<<<dim3(2, 17, N_B), 512, 0, stream>>>(x, ram, pda);
    k2<<<dim3(17, N_B), 256, 0, stream>>>(ram, pda, x, out);
}